// Round 1
// baseline (804.817 us; speedup 1.0000x reference)
//
#include <hip/hip_runtime.h>

// CTC forward loss, B=512, T=1024, C=256, L=64, S=129, blank=C-1.
// One wave (64 lanes) per batch element. Lane i holds alpha[2i] (even) and
// alpha[2i+1] (odd); lane 63 additionally holds alpha[128].
// Per step: ao_up = shfl_up(alpha_odd) provides alpha[s-1]/alpha[s-2].
// Register ring-buffer prefetch (depth 16) hides HBM gather latency.

#define EPS 1e-7f
#define NEG -1e30f

constexpr int Bb = 512;
constexpr int Tt = 1024;
constexpr int Cc = 256;
constexpr int Ll = 64;
constexpr int BLANK = Cc - 1;
constexpr int DPF = 16; // prefetch depth (power of 2)

__global__ __launch_bounds__(64) void ctc_fwd_kernel(
    const int* __restrict__ y_true,   // [B, L] int32
    const float* __restrict__ y_pred, // [B, T, C] float32 (probabilities)
    float* __restrict__ out)          // [B] float32 (loss, i.e. [B,1])
{
    const int b = blockIdx.x;
    const int lane = threadIdx.x; // 0..63

    const float* __restrict__ row0 = y_pred + (size_t)b * Tt * Cc;

    // label for odd state 2*lane+1
    const int lab = y_true[b * Ll + lane];
    const int lab_prev = __shfl_up(lab, 1);
    // skip (s-2 -> s) allowed for odd states iff label != blank (always true,
    // labels < C-1) and label != previous label; lane 0: ext[-1] is blank pad.
    const bool allow = (lane == 0) ? true : (lab != lab_prev);

    // ---- t = 0 init ----
    {
        // only lane 0's states 0,1 are live
    }
    const float pb0 = row0[BLANK];
    const float pl0 = row0[lab];
    float ae = (lane == 0) ? __logf(pb0 + EPS) : NEG; // alpha[2i]
    float ao = (lane == 0) ? __logf(pl0 + EPS) : NEG; // alpha[2i+1]
    float a128 = NEG;                                 // alpha[128] (lane 63)

    // ---- prefetch ring buffers ----
    float pl[DPF], pb[DPF];
#pragma unroll
    for (int j = 0; j < DPF; ++j) {
        const int t = 1 + j;
        pl[j] = row0[t * Cc + lab];
        pb[j] = row0[t * Cc + BLANK];
    }

    int t = 1;

    auto step = [&](int slot, bool do_prefetch) {
        const float lpl = __logf(pl[slot] + EPS);
        const float lpb = __logf(pb[slot] + EPS);
        if (do_prefetch) {
            const int tn = t + DPF;
            if (tn < Tt) {
                pl[slot] = row0[tn * Cc + lab];
                pb[slot] = row0[tn * Cc + BLANK];
            }
        }
        float ao_up = __shfl_up(ao, 1);
        if (lane == 0) ao_up = NEG;

        // even state s=2i: from alpha[2i], alpha[2i-1]; no skip (blank)
        const float m2 = fmaxf(ae, ao_up);
        const float ne =
            m2 + __logf(__expf(ae - m2) + __expf(ao_up - m2)) + lpb;

        // odd state s=2i+1: from alpha[2i+1], alpha[2i], (allow) alpha[2i-1]
        const float a3 = allow ? ao_up : NEG;
        const float m3 = fmaxf(fmaxf(ao, ae), a3);
        const float no =
            m3 +
            __logf(__expf(ao - m3) + __expf(ae - m3) + __expf(a3 - m3)) +
            lpl;

        // state 128 (only lane 63 meaningful): from alpha[128], alpha[127]
        const float m1 = fmaxf(a128, ao);
        const float n128 =
            m1 + __logf(__expf(a128 - m1) + __expf(ao - m1)) + lpb;

        ae = ne;
        ao = no;
        a128 = n128;
        ++t;
    };

    // main: 63 chunks x 16 steps (t = 1 .. 1008)
    for (int chunk = 0; chunk < (Tt - 1) / DPF; ++chunk) {
#pragma unroll
        for (int k = 0; k < DPF; ++k) {
            step(k, true);
        }
    }
    // remainder: 15 steps (t = 1009 .. 1023), buffers already filled
#pragma unroll
    for (int k = 0; k < (Tt - 1) % DPF; ++k) {
        step(k, false);
    }

    if (lane == 63) {
        // total = logaddexp(alpha[S-1], alpha[S-2]) = lse(a128, ao)
        const float m = fmaxf(a128, ao);
        const float total = m + __logf(__expf(a128 - m) + __expf(ao - m));
        out[b] = -total;
    }
}

extern "C" void kernel_launch(void* const* d_in, const int* in_sizes, int n_in,
                              void* d_out, int out_size, void* d_ws,
                              size_t ws_size, hipStream_t stream) {
    const int* y_true = (const int*)d_in[0];    // [512,64] int32
    const float* y_pred = (const float*)d_in[1]; // [512,1024,256] fp32
    float* out = (float*)d_out;                  // [512] fp32

    ctc_fwd_kernel<<<dim3(Bb), dim3(64), 0, stream>>>(y_true, y_pred, out);
}

// Round 2
// 800.143 us; speedup vs baseline: 1.0058x; 1.0058x over previous
//
#include <hip/hip_runtime.h>
#include <stdint.h>

// CTC forward loss, B=512, T=1024, C=256, L=64, S=129, blank=C-1.
// One wave (64 lanes) per batch element. Lane i holds alpha[2i], alpha[2i+1];
// lane 63 additionally alpha[128]. Cross-state deps via one __shfl_up.
//
// R2 change: replace per-lane HBM gathers (latency-bound, ~16 transactions
// per instr) with coalesced row staging: one global_load_lds width=16 per t
// (64 lanes x 16B = the whole 1KB row) into a 32-row LDS ring, manual
// s_waitcnt vmcnt(31) pipelining (31-32 rows in flight per wave), per-lane
// label gather via ds_read from LDS, 2-steps-ahead register prefetch of the
// gathered values. Single wave per block -> no barriers needed.

#define EPS 1e-7f
#define NEG -1e30f

constexpr int Bb = 512;
constexpr int Tt = 1024;
constexpr int Cc = 256;
constexpr int Ll = 64;
constexpr int BLANK = Cc - 1;
constexpr int D = 32; // LDS ring depth in rows (32 x 1KB = 32 KiB)

// Wait until at most 31 vector-memory ops outstanding. Inline asm with
// "memory" clobber so the compiler neither reorders LDS reads across it nor
// inserts its own draining waits (global_load_lds has no register result,
// so the compiler does not track it).
#define WAITVM31() asm volatile("s_waitcnt vmcnt(31)" ::: "memory")

__device__ __forceinline__ void dma_row(const float* __restrict__ g,
                                        float* l) {
    // 64 lanes x 16B -> LDS base + lane*16 (wave-uniform base, contiguous).
    __builtin_amdgcn_global_load_lds(
        (const __attribute__((address_space(1))) void*)g,
        (__attribute__((address_space(3))) void*)l, 16, 0, 0);
}

__global__ __launch_bounds__(64) void ctc_fwd_kernel(
    const int* __restrict__ y_true,   // [B, L] int32
    const float* __restrict__ y_pred, // [B, T, C] float32 probabilities
    float* __restrict__ out)          // [B] float32
{
    const int b = blockIdx.x;
    const int lane = threadIdx.x; // 0..63

    const float* __restrict__ row0 = y_pred + (size_t)b * Tt * Cc;

    __shared__ float ring[D * Cc]; // 32 KiB

    // Label for odd state 2*lane+1. Consume it (shfl) BEFORE issuing DMAs so
    // the compiler's vmcnt wait for this load doesn't drain the DMA queue.
    const int lab = y_true[b * Ll + lane];
    const int lab_prev = __shfl_up(lab, 1);
    const bool allow = (lane == 0) ? true : (lab != lab_prev);

    // ---- prologue: issue rows 0..D-1 into slots 0..D-1 ----
    for (int t0 = 0; t0 < D; ++t0)
        dma_row(row0 + t0 * Cc + lane * 4, &ring[t0 * Cc]);

    WAITVM31(); // row 0 resident (31 younger loads may be outstanding)
    const float pl0 = ring[lab];
    const float pb0 = ring[BLANK];
    float ae = (lane == 0) ? __logf(pb0 + EPS) : NEG; // alpha[2i]
    float ao = (lane == 0) ? __logf(pl0 + EPS) : NEG; // alpha[2i+1]
    float a128 = NEG;                                 // alpha[128] (lane 63)

    dma_row(row0 + D * Cc + lane * 4, &ring[0]); // row D -> slot 0
    WAITVM31();                                  // row 1 resident
    float glA = ring[1 * Cc + lab];
    float gbA = ring[1 * Cc + BLANK];
    dma_row(row0 + (D + 1) * Cc + lane * 4, &ring[1 * Cc]); // row D+1
    WAITVM31();                                             // row 2 resident
    float glB = ring[2 * Cc + lab];
    float gbB = ring[2 * Cc + BLANK];

    auto update = [&](float gl, float gb) {
        const float lpl = __logf(gl + EPS);
        const float lpb = __logf(gb + EPS);
        float ao_up = __shfl_up(ao, 1);
        if (lane == 0) ao_up = NEG;

        // even state s=2i: from alpha[2i], alpha[2i-1]; emits blank
        const float m2 = fmaxf(ae, ao_up);
        const float ne =
            m2 + __logf(__expf(ae - m2) + __expf(ao_up - m2)) + lpb;

        // odd state s=2i+1: from alpha[2i+1], alpha[2i], (allow) alpha[2i-1]
        const float a3 = allow ? ao_up : NEG;
        const float m3 = fmaxf(fmaxf(ao, ae), a3);
        const float no =
            m3 +
            __logf(__expf(ao - m3) + __expf(ae - m3) + __expf(a3 - m3)) +
            lpl;

        // state 128 (lane 63): from alpha[128], alpha[127]; emits blank
        const float m1 = fmaxf(a128, ao);
        const float n128 =
            m1 + __logf(__expf(a128 - m1) + __expf(ao - m1)) + lpb;

        ae = ne;
        ao = no;
        a128 = n128;
    };

    // steps t = 1 .. 1022 in pairs; invariant at pair top: last issued
    // row (virtual) = t + D. Each body: compute step, issue row t+1+D into
    // slot (t+1)&31 (gathered one iteration ago -> safe), wait vmcnt(31)
    // (=> row t+2 resident), gather g_{t+2}.
    for (int t = 1; t <= Tt - 3; t += 2) {
        update(glA, gbA); // step t
        {
            const int tn = min(t + 1 + D, Tt - 1);
            dma_row(row0 + tn * Cc + lane * 4,
                    &ring[((t + 1) & (D - 1)) * Cc]);
            WAITVM31();
            const int s = (t + 2) & (D - 1);
            glA = ring[s * Cc + lab];
            gbA = ring[s * Cc + BLANK];
        }
        update(glB, gbB); // step t+1
        {
            const int tn = min(t + 2 + D, Tt - 1);
            dma_row(row0 + tn * Cc + lane * 4,
                    &ring[((t + 2) & (D - 1)) * Cc]);
            WAITVM31();
            const int s = (t + 3) & (D - 1);
            glB = ring[s * Cc + lab];
            gbB = ring[s * Cc + BLANK];
        }
    }
    // tail: step t = 1023 (glA holds g_1023, gathered in the last A-body)
    update(glA, gbA);

    if (lane == 63) {
        const float m = fmaxf(a128, ao);
        out[b] = -(m + __logf(__expf(a128 - m) + __expf(ao - m)));
    }
}

extern "C" void kernel_launch(void* const* d_in, const int* in_sizes, int n_in,
                              void* d_out, int out_size, void* d_ws,
                              size_t ws_size, hipStream_t stream) {
    const int* y_true = (const int*)d_in[0];     // [512,64] int32
    const float* y_pred = (const float*)d_in[1]; // [512,1024,256] fp32
    float* out = (float*)d_out;                  // [512] fp32

    ctc_fwd_kernel<<<dim3(Bb), dim3(64), 0, stream>>>(y_true, y_pred, out);
}